// Round 2
// baseline (564.610 us; speedup 1.0000x reference)
//
#include <hip/hip_runtime.h>
#include <hip/hip_bf16.h>

#define LN_EPS 1e-5f

typedef __bf16 bf16x8 __attribute__((ext_vector_type(8)));
typedef float  f32x4  __attribute__((ext_vector_type(4)));
typedef unsigned short u16;
typedef unsigned int u32;

__device__ __forceinline__ u16 f2bf(float f) {
    __bf16 b = (__bf16)f;
    return __builtin_bit_cast(u16, b);
}
__device__ __forceinline__ bf16x8 zero8() {
    bf16x8 v;
#pragma unroll
    for (int j = 0; j < 8; j++) v[j] = (__bf16)0.f;
    return v;
}
// tanh-form GELU: v * sigmoid(v*(1.59576912 + 0.07135482 v^2))
__device__ __forceinline__ float gelu_f(float v) {
    float t = v * fmaf(v * v, 0.0713548162726f, 1.5957691216057f);
    return v / (1.f + __expf(-t));
}

// ---------------------------------------------------------------------------
// prep: pack weights into bf16 MFMA B-fragment order (16x16x32).
// dst[((t*4+s)*64+l)*8+j] = bf16(src[(t*16+(l&15))*128 + s*32 + ((l>>4)&3)*8 + j])
// ---------------------------------------------------------------------------
__global__ __launch_bounds__(256) void prep_kernel(
    const float* __restrict__ qkv_w, const float* __restrict__ o1_w,
    const float* __restrict__ o2_w, u16* __restrict__ wq,
    u16* __restrict__ o1f, u16* __restrict__ o2f) {
    int i = blockIdx.x * 256 + threadIdx.x;
    if (i >= 81920) return;
    int j = i;
    const float* src;
    u16* dst;
    if (j < 49152) { src = qkv_w; dst = wq; }
    else if (j < 65536) { j -= 49152; src = o1_w; dst = o1f; }
    else { j -= 65536; src = o2_w; dst = o2f; }
    int jj = j & 7;
    int l  = (j >> 3) & 63;
    int s  = (j >> 9) & 3;
    int t  = j >> 11;
    int outc = t * 16 + (l & 15);
    int k    = s * 32 + ((l >> 4) & 3) * 8 + jj;
    dst[j] = f2bf(src[outc * 128 + k]);
}

// ---------------------------------------------------------------------------
// k1: qkv GEMM; q -> LDS A-layout -> drained to q_ws in FRAGMENT order;
// per-row LN; kT/vT transpose; k^T v accumulated in regs over 2 sub-tiles.
// RESTRUCTURED (R1): 256-thread blocks (4 waves), 32 rows per inner tile,
// 2 tiles per block looped with register kv accumulation -> LDS 25600B
// -> 6 blocks/CU resident (vs 2-3 at 512thr/51KB). part layout unchanged.
// grid 2048 = B * (N/64); block 256 (2 row-stripes x 2 head-halves)
// ---------------------------------------------------------------------------
__global__ __launch_bounds__(256, 6) void k1(
    const float* __restrict__ x, const u16* __restrict__ wq,
    const float* __restrict__ qkv_b,
    const float* __restrict__ klw, const float* __restrict__ klb,
    const float* __restrict__ vlw, const float* __restrict__ vlb,
    u16* __restrict__ q_ws, float* __restrict__ part) {
    __shared__ __align__(16) char Rbuf[25600];
    u16* x_a  = (u16*)Rbuf;            // [32 n][136] (phase 1-2)
    u16* kv_s = (u16*)Rbuf;            // [32 n][264] cols h*32 + (k:0-15|v:16-31)
    u16* q_s  = (u16*)(Rbuf + 16896);  // [32 n][136] A-layout q
    u16* kT   = (u16*)Rbuf;            // [128 hd][40] (phase 5-6)
    u16* vT   = (u16*)(Rbuf + 10240);  // [128 hd][40]

    const int tid  = threadIdx.x;
    const int lane = tid & 63;
    const int wv   = tid >> 6;          // 0..3
    const int stripe = wv >> 1;         // 0..1 (16-row stripe)
    const int half   = wv & 1;          // head half
    const int bid  = blockIdx.x;
    const int b    = bid >> 8;
    const int tile0 = (bid & 255) * 64;

    const int m16  = stripe * 16;
    const int l15  = lane & 15;
    const int quad = lane >> 4;
    const int hL   = wv * 2 + (lane >> 5);  // LN head (2 heads per wave)
    const int rown = lane & 31;             // LN row

    f32x4 kvacc[2];
#pragma unroll
    for (int hh = 0; hh < 2; hh++) kvacc[hh] = (f32x4){0.f, 0.f, 0.f, 0.f};

    for (int it = 0; it < 2; ++it) {
        if (it) __syncthreads();   // phase-6 kT/vT reads done -> x_a overlay safe
        const int n0 = tile0 + it * 32;

        // phase 1: stage x -> x_a [32][136], packed b32 writes
        {
            int cw  = tid & 63;     // channel pair
            int sub = tid >> 6;     // n octet (0..3)
            const float* p0 = x + ((size_t)(b * 128 + 2 * cw)) * 16384 + n0 + sub * 8;
            const float* p1 = p0 + 16384;
            float4 a0 = ((const float4*)p0)[0], a1 = ((const float4*)p0)[1];
            float4 c0 = ((const float4*)p1)[0], c1 = ((const float4*)p1)[1];
            float av[8] = {a0.x, a0.y, a0.z, a0.w, a1.x, a1.y, a1.z, a1.w};
            float cv[8] = {c0.x, c0.y, c0.z, c0.w, c1.x, c1.y, c1.z, c1.w};
            u32* dst = (u32*)x_a;
#pragma unroll
            for (int j = 0; j < 8; j++)
                dst[(sub * 8 + j) * 68 + cw] = (u32)f2bf(av[j]) | ((u32)f2bf(cv[j]) << 16);
        }
        __syncthreads();

        // phase 2: A-frags
        bf16x8 af[4];
#pragma unroll
        for (int s = 0; s < 4; s++)
            af[s] = *(const bf16x8*)&x_a[(m16 + l15) * 136 + s * 32 + quad * 8];
        __syncthreads();   // x_a dead -> kv_s/q_s may be written

        // phase 3: qkv GEMM; q -> q_s (A-layout); k,v (+bias) -> kv_s
        const int tb = half * 12;
#pragma unroll
        for (int hh = 0; hh < 4; hh++) {
            const int tq = tb + 3 * hh;
            f32x4 aq  = (f32x4){0.f, 0.f, 0.f, 0.f};
            f32x4 ak  = (f32x4){0.f, 0.f, 0.f, 0.f};
            f32x4 avv = (f32x4){0.f, 0.f, 0.f, 0.f};
#pragma unroll
            for (int s = 0; s < 4; s++) {
                bf16x8 bq = *(const bf16x8*)(wq + (size_t)(((tq + 0) * 4 + s) * 64 + lane) * 8);
                bf16x8 bk = *(const bf16x8*)(wq + (size_t)(((tq + 1) * 4 + s) * 64 + lane) * 8);
                bf16x8 bv = *(const bf16x8*)(wq + (size_t)(((tq + 2) * 4 + s) * 64 + lane) * 8);
                aq  = __builtin_amdgcn_mfma_f32_16x16x32_bf16(af[s], bq, aq, 0, 0, 0);
                ak  = __builtin_amdgcn_mfma_f32_16x16x32_bf16(af[s], bk, ak, 0, 0, 0);
                avv = __builtin_amdgcn_mfma_f32_16x16x32_bf16(af[s], bv, avv, 0, 0, 0);
            }
            const int h = half * 4 + hh;
            float biasq = qkv_b[(tq + 0) * 16 + l15];
            float biask = qkv_b[(tq + 1) * 16 + l15];
            float biasv = qkv_b[(tq + 2) * 16 + l15];
#pragma unroll
            for (int r = 0; r < 4; r++) {
                int row = m16 + quad * 4 + r;
                q_s[row * 136 + h * 16 + l15]       = f2bf(aq[r] + biasq);
                kv_s[row * 264 + h * 32 + l15]      = f2bf(ak[r] + biask);
                kv_s[row * 264 + h * 32 + 16 + l15] = f2bf(avv[r] + biasv);
            }
        }
        __syncthreads();

        // phase 4a: drain q_s -> q_ws in fragment order (coalesced b128 stores)
        {
#pragma unroll
            for (int p = 0; p < 2; p++) {
                int c = tid + p * 256;           // chunk id, 512 total
                int lane_c = c & 63;
                int s  = (c >> 6) & 3;
                int tl = c >> 8;                 // local 16-row tile 0..1
                int row = tl * 16 + (lane_c & 15);
                const uint4* src = (const uint4*)&q_s[row * 136 + s * 32 + (lane_c >> 4) * 8];
                size_t gtile = (size_t)b * 1024 + (n0 >> 4) + tl;
                *(uint4*)(q_ws + gtile * 2048 + s * 512 + lane_c * 8) = *src;
            }
        }
        // phase 4b: per-row LN. thread = (head hL, row rown).
        const u16* rowp = &kv_s[rown * 264 + hL * 32];
        bf16x8 rk0 = *(const bf16x8*)(rowp);
        bf16x8 rk1 = *(const bf16x8*)(rowp + 8);
        bf16x8 rv0 = *(const bf16x8*)(rowp + 16);
        bf16x8 rv1 = *(const bf16x8*)(rowp + 24);
        __syncthreads();   // kv_s/q_s dead -> kT/vT overlay safe

        {
            float kf[16], vf[16];
#pragma unroll
            for (int j = 0; j < 8; j++) {
                kf[j] = (float)rk0[j]; kf[8 + j] = (float)rk1[j];
                vf[j] = (float)rv0[j]; vf[8 + j] = (float)rv1[j];
            }
            float ksum = 0.f, ksq = 0.f, vsum = 0.f, vsq = 0.f;
#pragma unroll
            for (int d = 0; d < 16; d++) {
                ksum += kf[d]; ksq = fmaf(kf[d], kf[d], ksq);
                vsum += vf[d]; vsq = fmaf(vf[d], vf[d], vsq);
            }
            float km = ksum * (1.f / 16.f);
            float kvar = (ksq - 16.f * km * km) * (1.f / 15.f);
            kvar = kvar < 0.f ? 0.f : kvar;
            float kinv = 1.f / (sqrtf(kvar) + LN_EPS);
            float vm = vsum * (1.f / 16.f);
            float vvar = (vsq - 16.f * vm * vm) * (1.f / 15.f);
            vvar = vvar < 0.f ? 0.f : vvar;
            float vinv = 1.f / (sqrtf(vvar) + LN_EPS);
            const float* kwp = klw + hL * 16; const float* kbp = klb + hL * 16;
            const float* vwp = vlw + hL * 16; const float* vbp = vlb + hL * 16;
#pragma unroll
            for (int d = 0; d < 16; d++) {
                kT[(hL * 16 + d) * 40 + rown] = f2bf(fmaf((kf[d] - km) * kinv, kwp[d], kbp[d]));
                vT[(hL * 16 + d) * 40 + rown] = f2bf(fmaf((vf[d] - vm) * vinv, vwp[d], vbp[d]));
            }
        }
        __syncthreads();

        // phase 6: kv partial, 2 heads per wave, K=32 (one MFMA per head)
#pragma unroll
        for (int hh = 0; hh < 2; hh++) {
            const int h = wv * 2 + hh;
            const u16* ka = &kT[(h * 16 + l15) * 40 + quad * 8];
            const u16* vb = &vT[(h * 16 + l15) * 40 + quad * 8];
            bf16x8 A0 = *(const bf16x8*)(ka);
            bf16x8 B0 = *(const bf16x8*)(vb);
            kvacc[hh] = __builtin_amdgcn_mfma_f32_16x16x32_bf16(A0, B0, kvacc[hh], 0, 0, 0);
        }
    }

    // store kv partials (layout identical to previous version)
#pragma unroll
    for (int hh = 0; hh < 2; hh++) {
        const int h = wv * 2 + hh;
        ((f32x4*)part)[(size_t)(bid * 8 + h) * 64 + lane] = kvacc[hh];
    }
}

// ---------------------------------------------------------------------------
// k_red: kv = (1/N) * sum over 256 tiles; emit bf16 B-fragment layout.
// grid 256 = b(8) x eg(32); block 256 = tchunk(4) x el(64); LDS combine.
// ---------------------------------------------------------------------------
__global__ __launch_bounds__(256) void k_red(const float* __restrict__ part,
                                             u16* __restrict__ kvf) {
    __shared__ float red[256];
    int tid = threadIdx.x;
    int b  = blockIdx.x >> 5;
    int eg = blockIdx.x & 31;
    int el = tid & 63;
    int tchunk = tid >> 6;
    int e = eg * 64 + el;
    int h = e >> 8, dk = (e >> 4) & 15, dv = e & 15;
    size_t off = (size_t)h * 256 + (size_t)(((dk >> 2) * 16 + dv) * 4 + (dk & 3));
    float s = 0.f;
#pragma unroll 8
    for (int t = tchunk * 64; t < tchunk * 64 + 64; t++)
        s += part[((size_t)(b * 256 + t)) * 2048 + off];
    red[tid] = s;
    __syncthreads();
    if (tid < 64) {
        float total = red[tid] + red[tid + 64] + red[tid + 128] + red[tid + 192];
        int e2 = eg * 64 + tid;
        int h2 = e2 >> 8, dk2 = (e2 >> 4) & 15, dv2 = e2 & 15;
        kvf[(size_t)(b * 8 + h2) * 256 + (dk2 >> 3) * 128 + dv2 * 8 + (dk2 & 7)] =
            f2bf(total * (1.f / 16384.f));
    }
}

// ---------------------------------------------------------------------------
// k2: av = q@kv, ret = av+x, h1 = gelu(ret@o1^T+b1), out = h1@o2^T+b2+x
// q A-frags read DIRECTLY from global (fragment-order q_ws), hoisted before
// the staging barrier. grid 4096 = B*(N/32); block 256 (2 stripes x 2 halves)
// ---------------------------------------------------------------------------
__global__ __launch_bounds__(256, 5) void k2(
    const float* __restrict__ x, const u16* __restrict__ q_ws,
    const u16* __restrict__ kvf, const u16* __restrict__ o1f,
    const u16* __restrict__ o2f, const float* __restrict__ o1_b,
    const float* __restrict__ o2_b, float* __restrict__ out) {
    __shared__ u16 a_s[32 * 136];      // ret -> h1 (A-layout)
    __shared__ float x_s[128 * 36];    // x [c][n]; becomes out in place

    const int tid  = threadIdx.x;
    const int lane = tid & 63;
    const int wv   = tid >> 6;
    const int stripe = wv >> 1;
    const int half   = wv & 1;
    const int bid  = blockIdx.x;
    const int b    = bid >> 9;
    const int n0   = (bid & 511) * 32;

    const int m16  = stripe * 16;
    const int l15  = lane & 15;
    const int quad = lane >> 4;
    const bool act = quad < 2;

    // hoisted global frag loads (independent of LDS): q A-frags + kv B-frags
    bf16x8 qf[4], kvb[4];
    {
        size_t gtile = (size_t)b * 1024 + (n0 >> 4) + stripe;
#pragma unroll
        for (int hh = 0; hh < 4; hh++) {
            int h = half * 4 + hh;
            if (act) {
                int laneq = ((h & 1) * 2 + quad) * 16 + l15;
                qf[hh]  = *(const bf16x8*)(q_ws + gtile * 2048 + (h >> 1) * 512 + laneq * 8);
                kvb[hh] = *(const bf16x8*)(kvf + (size_t)(b * 8 + h) * 256 + quad * 128 + l15 * 8);
            } else {
                qf[hh] = zero8(); kvb[hh] = zero8();
            }
        }
    }

    // stage x
    {
        int c = tid >> 1, nh = (tid & 1) * 16;
        const float4* xs = (const float4*)(x + ((size_t)(b * 128 + c)) * 16384 + n0 + nh);
        float4* xd = (float4*)&x_s[c * 36 + nh];
#pragma unroll
        for (int i = 0; i < 4; i++) xd[i] = xs[i];
    }
    __syncthreads();

    // av per head (4 heads per wave), ret = av + x
#pragma unroll
    for (int hh = 0; hh < 4; hh++) {
        int h = half * 4 + hh;
        f32x4 acc = __builtin_amdgcn_mfma_f32_16x16x32_bf16(
            qf[hh], kvb[hh], (f32x4){0.f,0.f,0.f,0.f}, 0, 0, 0);
#pragma unroll
        for (int r = 0; r < 4; r++) {
            float rv = acc[r] + x_s[(h * 16 + l15) * 36 + m16 + quad * 4 + r];
            a_s[(m16 + quad * 4 + r) * 136 + h * 16 + l15] = f2bf(rv);
        }
    }
    __syncthreads();

    // o1: 4 t-tiles per wave over full-128 rows
    bf16x8 af2[4];
#pragma unroll
    for (int s = 0; s < 4; s++)
        af2[s] = *(const bf16x8*)&a_s[(m16 + l15) * 136 + s * 32 + quad * 8];
    f32x4 acc2[4];
#pragma unroll
    for (int t = 0; t < 4; t++) acc2[t] = (f32x4){0.f,0.f,0.f,0.f};
#pragma unroll
    for (int tt = 0; tt < 4; tt++) {
        int t = half * 4 + tt;
#pragma unroll
        for (int s = 0; s < 4; s++) {
            bf16x8 bf = *(const bf16x8*)(o1f + (size_t)((t * 4 + s) * 64 + lane) * 8);
            acc2[tt] = __builtin_amdgcn_mfma_f32_16x16x32_bf16(af2[s], bf, acc2[tt], 0, 0, 0);
        }
    }
    float g[4][4];
#pragma unroll
    for (int tt = 0; tt < 4; tt++) {
        float bb = o1_b[(half * 4 + tt) * 16 + l15];
#pragma unroll
        for (int r = 0; r < 4; r++)
            g[tt][r] = gelu_f(acc2[tt][r] + bb);
    }
    __syncthreads();    // all ret-fragment reads done
#pragma unroll
    for (int tt = 0; tt < 4; tt++)
#pragma unroll
        for (int r = 0; r < 4; r++)
            a_s[(m16 + quad * 4 + r) * 136 + (half * 4 + tt) * 16 + l15] = f2bf(g[tt][r]);
    __syncthreads();

    // o2: out = h1 @ o2^T + b2 + x  (in place in x_s)
#pragma unroll
    for (int s = 0; s < 4; s++)
        af2[s] = *(const bf16x8*)&a_s[(m16 + l15) * 136 + s * 32 + quad * 8];
#pragma unroll
    for (int t = 0; t < 4; t++) acc2[t] = (f32x4){0.f,0.f,0.f,0.f};
#pragma unroll
    for (int tt = 0; tt < 4; tt++) {
        int t = half * 4 + tt;
#pragma unroll
        for (int s = 0; s < 4; s++) {
            bf16x8 bf = *(const bf16x8*)(o2f + (size_t)((t * 4 + s) * 64 + lane) * 8);
            acc2[tt] = __builtin_amdgcn_mfma_f32_16x16x32_bf16(af2[s], bf, acc2[tt], 0, 0, 0);
        }
    }
#pragma unroll
    for (int tt = 0; tt < 4; tt++) {
        int t = half * 4 + tt;
        float bb = o2_b[t * 16 + l15];
#pragma unroll
        for (int r = 0; r < 4; r++) {
            int row = m16 + quad * 4 + r;
            int col = t * 16 + l15;
            x_s[col * 36 + row] = acc2[tt][r] + bb + x_s[col * 36 + row];
        }
    }
    __syncthreads();

    // store, coalesced fp32 [c][n]
    {
        int c = tid >> 1, nh = (tid & 1) * 16;
        float4* dst = (float4*)(out + ((size_t)(b * 128 + c)) * 16384 + n0 + nh);
        const float4* sv = (const float4*)&x_s[c * 36 + nh];
#pragma unroll
        for (int i = 0; i < 4; i++) dst[i] = sv[i];
    }
}

// ---------------------------------------------------------------------------
extern "C" void kernel_launch(void* const* d_in, const int* in_sizes, int n_in,
                              void* d_out, int out_size, void* d_ws, size_t ws_size,
                              hipStream_t stream) {
    (void)in_sizes; (void)n_in; (void)out_size; (void)ws_size;
    const float* x     = (const float*)d_in[0];
    const float* qkv_w = (const float*)d_in[1];
    const float* qkv_b = (const float*)d_in[2];
    const float* o1_w  = (const float*)d_in[3];
    const float* o1_b  = (const float*)d_in[4];
    const float* o2_w  = (const float*)d_in[5];
    const float* o2_b  = (const float*)d_in[6];
    const float* klw   = (const float*)d_in[7];
    const float* klb   = (const float*)d_in[8];
    const float* vlw   = (const float*)d_in[9];
    const float* vlb   = (const float*)d_in[10];
    float* outp = (float*)d_out;

    char* ws = (char*)d_ws;
    u16*   kvf  = (u16*)(ws);                     // 16384 bf16 (32 KB)
    u16*   wq   = (u16*)(ws + 32768);             // 49152 bf16 (96 KB)
    u16*   o1f  = (u16*)(ws + 131072);            // 16384 bf16 (32 KB)
    u16*   o2f  = (u16*)(ws + 163840);            // 16384 bf16 (32 KB)
    float* part = (float*)(ws + 196608);          // 2048*2048 f (16 MB)
    u16*   q_ws = (u16*)(ws + 196608 + 16777216); // 8*16384*128 bf16 (32 MB)

    prep_kernel<<<320, 256, 0, stream>>>(qkv_w, o1_w, o2_w, wq, o1f, o2f);
    k1<<<2048, 256, 0, stream>>>(x, wq, qkv_b, klw, klb, vlw, vlb, q_ws, part);
    k_red<<<256, 256, 0, stream>>>(part, kvf);
    k2<<<4096, 256, 0, stream>>>(x, q_ws, kvf, o1f, o2f, o1_b, o2_b, outp);
}

// Round 3
// 205.513 us; speedup vs baseline: 2.7473x; 2.7473x over previous
//
#include <hip/hip_runtime.h>
#include <hip/hip_bf16.h>

#define LN_EPS 1e-5f

typedef __bf16 bf16x8 __attribute__((ext_vector_type(8)));
typedef float  f32x4  __attribute__((ext_vector_type(4)));
typedef unsigned short u16;
typedef unsigned int u32;

__device__ __forceinline__ u16 f2bf(float f) {
    __bf16 b = (__bf16)f;
    return __builtin_bit_cast(u16, b);
}
__device__ __forceinline__ bf16x8 zero8() {
    bf16x8 v;
#pragma unroll
    for (int j = 0; j < 8; j++) v[j] = (__bf16)0.f;
    return v;
}
// tanh-form GELU: v * sigmoid(v*(1.59576912 + 0.07135482 v^2))
__device__ __forceinline__ float gelu_f(float v) {
    float t = v * fmaf(v * v, 0.0713548162726f, 1.5957691216057f);
    return v / (1.f + __expf(-t));
}

// ---------------------------------------------------------------------------
// prep: pack weights into bf16 MFMA B-fragment order (16x16x32).
// dst[((t*4+s)*64+l)*8+j] = bf16(src[(t*16+(l&15))*128 + s*32 + ((l>>4)&3)*8 + j])
// ---------------------------------------------------------------------------
__global__ __launch_bounds__(256) void prep_kernel(
    const float* __restrict__ qkv_w, const float* __restrict__ o1_w,
    const float* __restrict__ o2_w, u16* __restrict__ wq,
    u16* __restrict__ o1f, u16* __restrict__ o2f) {
    int i = blockIdx.x * 256 + threadIdx.x;
    if (i >= 81920) return;
    int j = i;
    const float* src;
    u16* dst;
    if (j < 49152) { src = qkv_w; dst = wq; }
    else if (j < 65536) { j -= 49152; src = o1_w; dst = o1f; }
    else { j -= 65536; src = o2_w; dst = o2f; }
    int jj = j & 7;
    int l  = (j >> 3) & 63;
    int s  = (j >> 9) & 3;
    int t  = j >> 11;
    int outc = t * 16 + (l & 15);
    int k    = s * 32 + ((l >> 4) & 3) * 8 + jj;
    dst[j] = f2bf(src[outc * 128 + k]);
}

// ---------------------------------------------------------------------------
// k1: REVERTED to the proven R1 512-thread straight-line version (60 us).
// R2's looped 256-thread variant spilled ~0.5 KB/thread/iter to scratch
// (symmetric +540 MB FETCH/WRITE) -> 404 us. Straight-line allocation is
// load-bearing here; do not wrap phases in loops.
// grid 2048 = B * (N/64); block 512 (8 waves: 4 row-stripes x 2 head-halves)
// LDS 51200B: [kv_s 33792 | q_s 17408]; x_a and kT/vT overlay kv_s/q_s.
// ---------------------------------------------------------------------------
__global__ __launch_bounds__(512, 6) void k1(
    const float* __restrict__ x, const u16* __restrict__ wq,
    const float* __restrict__ qkv_b,
    const float* __restrict__ klw, const float* __restrict__ klb,
    const float* __restrict__ vlw, const float* __restrict__ vlb,
    u16* __restrict__ q_ws, float* __restrict__ part) {
    __shared__ __align__(16) char Rbuf[51200];
    u16* x_a  = (u16*)Rbuf;            // [64 n][136] (phase 1-2)
    u16* kv_s = (u16*)Rbuf;            // [64 n][264] cols h*32 + (k:0-15|v:16-31)
    u16* q_s  = (u16*)(Rbuf + 33792);  // [64 n][136] A-layout q
    u16* kT   = (u16*)Rbuf;            // [128 hd][72] (phase 5-6)
    u16* vT   = (u16*)(Rbuf + 18432);  // [128 hd][72]

    const int tid  = threadIdx.x;
    const int lane = tid & 63;
    const int wv   = tid >> 6;
    const int stripe = wv >> 1;
    const int half   = wv & 1;
    const int bid  = blockIdx.x;
    const int b    = bid >> 8;
    const int n0   = (bid & 255) * 64;

    // phase 1: stage x -> x_a, packed b32 writes (conflict-free)
    {
        int cw  = tid & 63;     // channel pair
        int sub = tid >> 6;     // n octet
        const float* p0 = x + ((size_t)(b * 128 + 2 * cw)) * 16384 + n0 + sub * 8;
        const float* p1 = p0 + 16384;
        float4 a0 = ((const float4*)p0)[0], a1 = ((const float4*)p0)[1];
        float4 c0 = ((const float4*)p1)[0], c1 = ((const float4*)p1)[1];
        float av[8] = {a0.x, a0.y, a0.z, a0.w, a1.x, a1.y, a1.z, a1.w};
        float cv[8] = {c0.x, c0.y, c0.z, c0.w, c1.x, c1.y, c1.z, c1.w};
        u32* dst = (u32*)x_a;
#pragma unroll
        for (int j = 0; j < 8; j++)
            dst[(sub * 8 + j) * 68 + cw] = (u32)f2bf(av[j]) | ((u32)f2bf(cv[j]) << 16);
    }
    __syncthreads();

    const int m16  = stripe * 16;
    const int l15  = lane & 15;
    const int quad = lane >> 4;

    bf16x8 af[4];
#pragma unroll
    for (int s = 0; s < 4; s++)
        af[s] = *(const bf16x8*)&x_a[(m16 + l15) * 136 + s * 32 + quad * 8];
    __syncthreads();   // x_a dead -> kv_s/q_s may be written

    // phase 3: qkv GEMM; q -> q_s (A-layout); k,v (+bias) -> kv_s
    const int tb = half * 12;
#pragma unroll
    for (int hh = 0; hh < 4; hh++) {
        const int tq = tb + 3 * hh;
        f32x4 aq  = (f32x4){0.f, 0.f, 0.f, 0.f};
        f32x4 ak  = (f32x4){0.f, 0.f, 0.f, 0.f};
        f32x4 avv = (f32x4){0.f, 0.f, 0.f, 0.f};
#pragma unroll
        for (int s = 0; s < 4; s++) {
            bf16x8 bq = *(const bf16x8*)(wq + (size_t)(((tq + 0) * 4 + s) * 64 + lane) * 8);
            bf16x8 bk = *(const bf16x8*)(wq + (size_t)(((tq + 1) * 4 + s) * 64 + lane) * 8);
            bf16x8 bv = *(const bf16x8*)(wq + (size_t)(((tq + 2) * 4 + s) * 64 + lane) * 8);
            aq  = __builtin_amdgcn_mfma_f32_16x16x32_bf16(af[s], bq, aq, 0, 0, 0);
            ak  = __builtin_amdgcn_mfma_f32_16x16x32_bf16(af[s], bk, ak, 0, 0, 0);
            avv = __builtin_amdgcn_mfma_f32_16x16x32_bf16(af[s], bv, avv, 0, 0, 0);
        }
        const int h = half * 4 + hh;
        float biasq = qkv_b[(tq + 0) * 16 + l15];
        float biask = qkv_b[(tq + 1) * 16 + l15];
        float biasv = qkv_b[(tq + 2) * 16 + l15];
#pragma unroll
        for (int r = 0; r < 4; r++) {
            int row = m16 + quad * 4 + r;
            q_s[row * 136 + h * 16 + l15]       = f2bf(aq[r] + biasq);
            kv_s[row * 264 + h * 32 + l15]      = f2bf(ak[r] + biask);
            kv_s[row * 264 + h * 32 + 16 + l15] = f2bf(avv[r] + biasv);
        }
    }
    __syncthreads();

    // phase 4a: drain q_s -> q_ws in fragment order (coalesced b128 stores)
    {
#pragma unroll
        for (int p = 0; p < 2; p++) {
            int c = tid + p * 512;           // chunk id, 1024 total
            int lane_c = c & 63;
            int s  = (c >> 6) & 3;
            int tl = c >> 8;                 // local tile 0..3
            int row = tl * 16 + (lane_c & 15);
            const uint4* src = (const uint4*)&q_s[row * 136 + s * 32 + (lane_c >> 4) * 8];
            size_t gtile = (size_t)b * 1024 + (n0 >> 4) + tl;
            *(uint4*)(q_ws + gtile * 2048 + s * 512 + lane_c * 8) = *src;
        }
    }
    // phase 4b: per-row LN. thread = (head hL = wave, row = lane).
    const int hL = __builtin_amdgcn_readfirstlane(wv);
    const u16* rowp = &kv_s[lane * 264 + hL * 32];
    bf16x8 rk0 = *(const bf16x8*)(rowp);
    bf16x8 rk1 = *(const bf16x8*)(rowp + 8);
    bf16x8 rv0 = *(const bf16x8*)(rowp + 16);
    bf16x8 rv1 = *(const bf16x8*)(rowp + 24);
    __syncthreads();   // kv_s/q_s dead -> kT/vT overlay safe

    {
        float kf[16], vf[16];
#pragma unroll
        for (int j = 0; j < 8; j++) {
            kf[j] = (float)rk0[j]; kf[8 + j] = (float)rk1[j];
            vf[j] = (float)rv0[j]; vf[8 + j] = (float)rv1[j];
        }
        float ksum = 0.f, ksq = 0.f, vsum = 0.f, vsq = 0.f;
#pragma unroll
        for (int d = 0; d < 16; d++) {
            ksum += kf[d]; ksq = fmaf(kf[d], kf[d], ksq);
            vsum += vf[d]; vsq = fmaf(vf[d], vf[d], vsq);
        }
        float km = ksum * (1.f / 16.f);
        float kvar = (ksq - 16.f * km * km) * (1.f / 15.f);
        kvar = kvar < 0.f ? 0.f : kvar;
        float kinv = 1.f / (sqrtf(kvar) + LN_EPS);
        float vm = vsum * (1.f / 16.f);
        float vvar = (vsq - 16.f * vm * vm) * (1.f / 15.f);
        vvar = vvar < 0.f ? 0.f : vvar;
        float vinv = 1.f / (sqrtf(vvar) + LN_EPS);
        const float* kwp = klw + hL * 16; const float* kbp = klb + hL * 16;
        const float* vwp = vlw + hL * 16; const float* vbp = vlb + hL * 16;
#pragma unroll
        for (int d = 0; d < 16; d++) {
            kT[(hL * 16 + d) * 72 + lane] = f2bf(fmaf((kf[d] - km) * kinv, kwp[d], kbp[d]));
            vT[(hL * 16 + d) * 72 + lane] = f2bf(fmaf((vf[d] - vm) * vinv, vwp[d], vbp[d]));
        }
    }
    __syncthreads();

    // phase 6: kv partial for head hL over all 64 rows: 2 MFMAs
    {
        const u16* ka = &kT[(hL * 16 + l15) * 72 + quad * 8];
        const u16* vb = &vT[(hL * 16 + l15) * 72 + quad * 8];
        bf16x8 A0 = *(const bf16x8*)(ka);
        bf16x8 A1 = *(const bf16x8*)(ka + 32);
        bf16x8 B0 = *(const bf16x8*)(vb);
        bf16x8 B1 = *(const bf16x8*)(vb + 32);
        f32x4 kv = __builtin_amdgcn_mfma_f32_16x16x32_bf16(A0, B0, (f32x4){0.f,0.f,0.f,0.f}, 0, 0, 0);
        kv = __builtin_amdgcn_mfma_f32_16x16x32_bf16(A1, B1, kv, 0, 0, 0);
        ((f32x4*)part)[(size_t)(bid * 8 + hL) * 64 + lane] = kv;
    }
}

// ---------------------------------------------------------------------------
// k_red (R3): coalesced f32x4 reduction. Each lane loads the exact f32x4 a
// k1 wave stored (contiguous 1 KB per wave -> full lines), vs the old 4B @
// 16B-stride pattern (25% sector efficiency, ~4x over-fetch of 16.8 MB).
// grid 64 = b(8) x h(8); block 256 = tchunk(4) x lane(64); LDS combine.
// Output kvf layout identical to previous version.
// ---------------------------------------------------------------------------
__global__ __launch_bounds__(256) void k_red(const float* __restrict__ part,
                                             u16* __restrict__ kvf) {
    __shared__ f32x4 red[4][64];
    const int tid  = threadIdx.x;
    const int lane = tid & 63;
    const int wvq  = tid >> 6;
    const int b = blockIdx.x >> 3;
    const int h = blockIdx.x & 7;

    const f32x4* p = (const f32x4*)part;
    f32x4 s = (f32x4){0.f, 0.f, 0.f, 0.f};
#pragma unroll 8
    for (int tt = 0; tt < 64; tt++) {
        int t = wvq * 64 + tt;
        f32x4 v = p[((size_t)(b * 256 + t) * 8 + h) * 64 + lane];
        s += v;
    }
    red[wvq][lane] = s;
    __syncthreads();
    if (tid < 64) {
        f32x4 tot = red[0][lane];
#pragma unroll
        for (int w = 1; w < 4; w++) tot += red[w][lane];
#pragma unroll
        for (int r = 0; r < 4; r++) {
            int dk = (lane >> 4) * 4 + r;
            int dv = lane & 15;
            kvf[(size_t)(b * 8 + h) * 256 + (dk >> 3) * 128 + dv * 8 + (dk & 7)] =
                f2bf(tot[r] * (1.f / 16384.f));
        }
    }
}

// ---------------------------------------------------------------------------
// k2: av = q@kv, ret = av+x, h1 = gelu(ret@o1^T+b1), out = h1@o2^T+b2+x
// q A-frags read DIRECTLY from global (fragment-order q_ws), hoisted before
// the staging barrier. grid 4096 = B*(N/32); block 256 (2 stripes x 2 halves)
// ---------------------------------------------------------------------------
__global__ __launch_bounds__(256, 5) void k2(
    const float* __restrict__ x, const u16* __restrict__ q_ws,
    const u16* __restrict__ kvf, const u16* __restrict__ o1f,
    const u16* __restrict__ o2f, const float* __restrict__ o1_b,
    const float* __restrict__ o2_b, float* __restrict__ out) {
    __shared__ u16 a_s[32 * 136];      // ret -> h1 (A-layout)
    __shared__ float x_s[128 * 36];    // x [c][n]; becomes out in place

    const int tid  = threadIdx.x;
    const int lane = tid & 63;
    const int wv   = tid >> 6;
    const int stripe = wv >> 1;
    const int half   = wv & 1;
    const int bid  = blockIdx.x;
    const int b    = bid >> 9;
    const int n0   = (bid & 511) * 32;

    const int m16  = stripe * 16;
    const int l15  = lane & 15;
    const int quad = lane >> 4;
    const bool act = quad < 2;

    // hoisted global frag loads (independent of LDS): q A-frags + kv B-frags
    bf16x8 qf[4], kvb[4];
    {
        size_t gtile = (size_t)b * 1024 + (n0 >> 4) + stripe;
#pragma unroll
        for (int hh = 0; hh < 4; hh++) {
            int h = half * 4 + hh;
            if (act) {
                int laneq = ((h & 1) * 2 + quad) * 16 + l15;
                qf[hh]  = *(const bf16x8*)(q_ws + gtile * 2048 + (h >> 1) * 512 + laneq * 8);
                kvb[hh] = *(const bf16x8*)(kvf + (size_t)(b * 8 + h) * 256 + quad * 128 + l15 * 8);
            } else {
                qf[hh] = zero8(); kvb[hh] = zero8();
            }
        }
    }

    // stage x
    {
        int c = tid >> 1, nh = (tid & 1) * 16;
        const float4* xs = (const float4*)(x + ((size_t)(b * 128 + c)) * 16384 + n0 + nh);
        float4* xd = (float4*)&x_s[c * 36 + nh];
#pragma unroll
        for (int i = 0; i < 4; i++) xd[i] = xs[i];
    }
    __syncthreads();

    // av per head (4 heads per wave), ret = av + x
#pragma unroll
    for (int hh = 0; hh < 4; hh++) {
        int h = half * 4 + hh;
        f32x4 acc = __builtin_amdgcn_mfma_f32_16x16x32_bf16(
            qf[hh], kvb[hh], (f32x4){0.f,0.f,0.f,0.f}, 0, 0, 0);
#pragma unroll
        for (int r = 0; r < 4; r++) {
            float rv = acc[r] + x_s[(h * 16 + l15) * 36 + m16 + quad * 4 + r];
            a_s[(m16 + quad * 4 + r) * 136 + h * 16 + l15] = f2bf(rv);
        }
    }
    __syncthreads();

    // o1: 4 t-tiles per wave over full-128 rows
    bf16x8 af2[4];
#pragma unroll
    for (int s = 0; s < 4; s++)
        af2[s] = *(const bf16x8*)&a_s[(m16 + l15) * 136 + s * 32 + quad * 8];
    f32x4 acc2[4];
#pragma unroll
    for (int t = 0; t < 4; t++) acc2[t] = (f32x4){0.f,0.f,0.f,0.f};
#pragma unroll
    for (int tt = 0; tt < 4; tt++) {
        int t = half * 4 + tt;
#pragma unroll
        for (int s = 0; s < 4; s++) {
            bf16x8 bf = *(const bf16x8*)(o1f + (size_t)((t * 4 + s) * 64 + lane) * 8);
            acc2[tt] = __builtin_amdgcn_mfma_f32_16x16x32_bf16(af2[s], bf, acc2[tt], 0, 0, 0);
        }
    }
    float g[4][4];
#pragma unroll
    for (int tt = 0; tt < 4; tt++) {
        float bb = o1_b[(half * 4 + tt) * 16 + l15];
#pragma unroll
        for (int r = 0; r < 4; r++)
            g[tt][r] = gelu_f(acc2[tt][r] + bb);
    }
    __syncthreads();    // all ret-fragment reads done
#pragma unroll
    for (int tt = 0; tt < 4; tt++)
#pragma unroll
        for (int r = 0; r < 4; r++)
            a_s[(m16 + quad * 4 + r) * 136 + (half * 4 + tt) * 16 + l15] = f2bf(g[tt][r]);
    __syncthreads();

    // o2: out = h1 @ o2^T + b2 + x  (in place in x_s)
#pragma unroll
    for (int s = 0; s < 4; s++)
        af2[s] = *(const bf16x8*)&a_s[(m16 + l15) * 136 + s * 32 + quad * 8];
#pragma unroll
    for (int t = 0; t < 4; t++) acc2[t] = (f32x4){0.f,0.f,0.f,0.f};
#pragma unroll
    for (int tt = 0; tt < 4; tt++) {
        int t = half * 4 + tt;
#pragma unroll
        for (int s = 0; s < 4; s++) {
            bf16x8 bf = *(const bf16x8*)(o2f + (size_t)((t * 4 + s) * 64 + lane) * 8);
            acc2[tt] = __builtin_amdgcn_mfma_f32_16x16x32_bf16(af2[s], bf, acc2[tt], 0, 0, 0);
        }
    }
#pragma unroll
    for (int tt = 0; tt < 4; tt++) {
        int t = half * 4 + tt;
        float bb = o2_b[t * 16 + l15];
#pragma unroll
        for (int r = 0; r < 4; r++) {
            int row = m16 + quad * 4 + r;
            int col = t * 16 + l15;
            x_s[col * 36 + row] = acc2[tt][r] + bb + x_s[col * 36 + row];
        }
    }
    __syncthreads();

    // store, coalesced fp32 [c][n]
    {
        int c = tid >> 1, nh = (tid & 1) * 16;
        float4* dst = (float4*)(out + ((size_t)(b * 128 + c)) * 16384 + n0 + nh);
        const float4* sv = (const float4*)&x_s[c * 36 + nh];
#pragma unroll
        for (int i = 0; i < 4; i++) dst[i] = sv[i];
    }
}

// ---------------------------------------------------------------------------
extern "C" void kernel_launch(void* const* d_in, const int* in_sizes, int n_in,
                              void* d_out, int out_size, void* d_ws, size_t ws_size,
                              hipStream_t stream) {
    (void)in_sizes; (void)n_in; (void)out_size; (void)ws_size;
    const float* x     = (const float*)d_in[0];
    const float* qkv_w = (const float*)d_in[1];
    const float* qkv_b = (const float*)d_in[2];
    const float* o1_w  = (const float*)d_in[3];
    const float* o1_b  = (const float*)d_in[4];
    const float* o2_w  = (const float*)d_in[5];
    const float* o2_b  = (const float*)d_in[6];
    const float* klw   = (const float*)d_in[7];
    const float* klb   = (const float*)d_in[8];
    const float* vlw   = (const float*)d_in[9];
    const float* vlb   = (const float*)d_in[10];
    float* outp = (float*)d_out;

    char* ws = (char*)d_ws;
    u16*   kvf  = (u16*)(ws);                     // 16384 bf16 (32 KB)
    u16*   wq   = (u16*)(ws + 32768);             // 49152 bf16 (96 KB)
    u16*   o1f  = (u16*)(ws + 131072);            // 16384 bf16 (32 KB)
    u16*   o2f  = (u16*)(ws + 163840);            // 16384 bf16 (32 KB)
    float* part = (float*)(ws + 196608);          // 2048*2048 f (16 MB)
    u16*   q_ws = (u16*)(ws + 196608 + 16777216); // 8*16384*128 bf16 (32 MB)

    prep_kernel<<<320, 256, 0, stream>>>(qkv_w, o1_w, o2_w, wq, o1f, o2f);
    k1<<<2048, 512, 0, stream>>>(x, wq, qkv_b, klw, klb, vlw, vlb, q_ws, part);
    k_red<<<64, 256, 0, stream>>>(part, kvf);
    k2<<<4096, 256, 0, stream>>>(x, q_ws, kvf, o1f, o2f, o1_b, o2_b, outp);
}